// Round 2
// baseline (1573.428 us; speedup 1.0000x reference)
//
#include <hip/hip_runtime.h>

// Problem constants (from reference):
//   T=26 tables, R=100000 rows, D=128 dim, B=4096 batch, L=20 bag size
//   MODES alternate [SUM, MEAN, ...] -> mode = t & 1
constexpr int T = 26;
constexpr int R = 100000;
constexpr int D = 128;
constexpr int B = 4096;
constexpr int L = 20;

// Two bags per 32-lane group. Each lane owns a float4 (16 B); 32 lanes = one
// full 512 B row per load instruction. A wave (64 lanes) therefore has FOUR
// bags in flight (2 per half-wave), i.e. 40 independent 1 KB row loads.
// Indices are loaded as int4 (5 VMEM instr instead of 20) to shorten the
// index->address critical path.
// Block = 256 threads = 8 groups = 16 bags. Grid = T*B/16 = 6656 blocks.
__global__ __launch_bounds__(256, 4) void merged_embedding_bag_kernel(
    const float* __restrict__ W,       // [T, R, D]
    const int*   __restrict__ indices, // [T, B, L] (int32)
    float*       __restrict__ out)     // [T, B, D]
{
    const int lane = threadIdx.x & 31;          // float4 slot within row
    const int grp  = threadIdx.x >> 5;          // 0..7
    const int pair = blockIdx.x * 8 + grp;      // bag-pair id in [0, T*B/2)
    const int g0   = pair * 2;                  // first bag id (even)
    const int t    = g0 >> 12;                  // g0 / 4096
    const int b0   = g0 & 4095;                 // even, so b0+1 stays in table t

    // 40 consecutive int32 indices (bags b0, b0+1), 16 B aligned (160 B stride
    // from any even bag boundary).
    const int4* idxp = (const int4*)(indices + ((size_t)t * B + b0) * L);
    // Per-lane base into table t, in float4 units. Row stride = 32 float4.
    const float4* wl = (const float4*)(W + (size_t)t * R * D) + lane;

    int4 iv[10];
#pragma unroll
    for (int k = 0; k < 10; ++k) iv[k] = idxp[k];

    int idx[40];
#pragma unroll
    for (int k = 0; k < 10; ++k) {
        idx[4 * k + 0] = iv[k].x;
        idx[4 * k + 1] = iv[k].y;
        idx[4 * k + 2] = iv[k].z;
        idx[4 * k + 3] = iv[k].w;
    }
    // idx[0..19] = bag A, idx[20..39] = bag B

    float4 accA = make_float4(0.f, 0.f, 0.f, 0.f);
    float4 accB = make_float4(0.f, 0.f, 0.f, 0.f);
#pragma unroll
    for (int l = 0; l < 20; ++l) {
        float4 va = wl[(size_t)idx[l]      * 32];
        float4 vb = wl[(size_t)idx[20 + l] * 32];
        accA.x += va.x; accA.y += va.y; accA.z += va.z; accA.w += va.w;
        accB.x += vb.x; accB.y += vb.y; accB.z += vb.z; accB.w += vb.w;
    }

    // MEAN pooling for odd tables, SUM for even (both bags share table t).
    const float scale = (t & 1) ? (1.0f / (float)L) : 1.0f;
    accA.x *= scale; accA.y *= scale; accA.z *= scale; accA.w *= scale;
    accB.x *= scale; accB.y *= scale; accB.z *= scale; accB.w *= scale;

    float4* opA = (float4*)(out + ((size_t)t * B + b0) * D) + lane;
    opA[0]  = accA;
    opA[32] = accB;  // bag b0+1, +128 floats
}

extern "C" void kernel_launch(void* const* d_in, const int* in_sizes, int n_in,
                              void* d_out, int out_size, void* d_ws, size_t ws_size,
                              hipStream_t stream) {
    const float* W       = (const float*)d_in[0];
    const int*   indices = (const int*)d_in[1];
    float*       out     = (float*)d_out;

    const int bags   = T * B;          // 106496
    const int blocks = bags / 16;      // 6656 (exact)
    merged_embedding_bag_kernel<<<blocks, 256, 0, stream>>>(W, indices, out);
}